// Round 2
// baseline (4082.082 us; speedup 1.0000x reference)
//
#include <hip/hip_runtime.h>

#define N_NODES 50000
#define N_EDGES 800000
#define C 128
#define NLAYERS 3
#define KOUT 10
#define BN_EPS 1e-5f

// ---------- dtype helpers ----------
__device__ __forceinline__ float bf2f(unsigned short u) {
    return __uint_as_float(((unsigned int)u) << 16);
}
__device__ __forceinline__ unsigned short f2bf(float f) {
    unsigned int b = __float_as_uint(f);
    b += 0x7fff + ((b >> 16) & 1);   // round-to-nearest-even
    return (unsigned short)(b >> 16);
}
// flag-aware scalar loads (branch is wave-uniform: flags are the same for all lanes)
__device__ __forceinline__ float loadf(const void* p, long long i, int bf) {
    return bf ? bf2f(((const unsigned short*)p)[i]) : ((const float*)p)[i];
}
__device__ __forceinline__ int loadi(const void* p, long long i, int i64) {
    return i64 ? (int)((const long long*)p)[i] : ((const int*)p)[i];
}

// ---------- runtime dtype detection ----------
// gamma is all-ones: fp32 word0 = 0x3F800000, bf16 word0 = 0x3F803F80.
// edge_index values < 50000: if int64, odd 32-bit words of first 63 elements are all 0.
__global__ void detect_kernel(const unsigned int* __restrict__ gbits,
                              const unsigned int* __restrict__ ebits,
                              int* __restrict__ flags) {
    __shared__ int nz;
    if (threadIdx.x == 0) nz = 0;
    __syncthreads();
    if (threadIdx.x < 63 && ebits[threadIdx.x * 2 + 1] != 0u) atomicAdd(&nz, 1);
    __syncthreads();
    if (threadIdx.x == 0) {
        flags[0] = (gbits[0] == 0x3F803F80u) ? 1 : 0;  // 1 = float tensors are bf16
        flags[1] = (nz == 0) ? 1 : 0;                  // 1 = edge_index is int64
    }
}

// ---------- h = x @ node_W.T + node_b  (h canonical fp32 in ws) ----------
__global__ __launch_bounds__(256) void node_embed_kernel(
    const void* __restrict__ x, const void* __restrict__ node_W,
    const void* __restrict__ node_b, float* __restrict__ h,
    const int* __restrict__ flags) {
    int f = flags[0];
    int gtid = blockIdx.x * blockDim.x + threadIdx.x;
    int n = gtid >> 5;
    if (n >= N_NODES) return;
    int c0 = (gtid & 31) * 4;
    float xv[7];
#pragma unroll
    for (int j = 0; j < 7; ++j) xv[j] = loadf(x, (long long)n * 7 + j, f);
    float4 acc;
    float* ap = (float*)&acc;
#pragma unroll
    for (int i = 0; i < 4; ++i) {
        int c = c0 + i;
        float a = loadf(node_b, c, f);
#pragma unroll
        for (int j = 0; j < 7; ++j) a = fmaf(xv[j], loadf(node_W, (long long)c * 7 + j, f), a);
        ap[i] = a;
    }
    ((float4*)h)[(long long)n * 32 + (gtid & 31)] = acc;
}

// ---------- pack Wcat[l][o][k]: rows [Wfi;Wsi;Wfj;Wsj] (fp32 in ws) ----------
__global__ void pack_wcat_kernel(const void* __restrict__ Wf,
                                 const void* __restrict__ Ws,
                                 float* __restrict__ Wcat,
                                 const int* __restrict__ flags) {
    int f = flags[0];
    int idx = blockIdx.x * blockDim.x + threadIdx.x;
    if (idx >= NLAYERS * 512 * C) return;
    int k = idx & 127;
    int o = (idx >> 7) & 511;
    int l = idx >> 16;            // 512*128 = 65536 per layer
    int c = o & 127;
    int g = o >> 7;               // 0:Wfi 1:Wsi 2:Wfj 3:Wsj
    long long base = (long long)l * C * 3 * C + (long long)c * 3 * C;
    float v;
    if (g == 0)      v = loadf(Wf, base + k, f);
    else if (g == 1) v = loadf(Ws, base + k, f);
    else if (g == 2) v = loadf(Wf, base + C + k, f);
    else             v = loadf(Ws, base + C + k, f);
    Wcat[idx] = v;
}

// ---------- fold edge path: Wfold[b][j][c], bfold[b][c] (fp32 in ws) ----------
__global__ void fold_edge_kernel(const void* __restrict__ Wf,
                                 const void* __restrict__ Ws,
                                 const void* __restrict__ bf,
                                 const void* __restrict__ bs,
                                 const void* __restrict__ edge_W,
                                 const void* __restrict__ edge_b,
                                 float* __restrict__ Wfold,
                                 float* __restrict__ bfold,
                                 const int* __restrict__ flags) {
    int f = flags[0];
    int b = blockIdx.x;           // 2*NLAYERS blocks
    int l = b >> 1;
    int s = b & 1;
    int c = threadIdx.x;          // 128 threads
    const void* W = s ? Ws : Wf;
    const void* bias = s ? bs : bf;
    long long wbase = (long long)l * C * 3 * C + (long long)c * 3 * C + 2 * C;
    float acc[6] = {0.f, 0.f, 0.f, 0.f, 0.f, 0.f};
    float bacc = 0.f;
    for (int k = 0; k < C; ++k) {
        float w = loadf(W, wbase + k, f);
#pragma unroll
        for (int j = 0; j < 6; ++j) acc[j] = fmaf(w, loadf(edge_W, k * 6 + j, f), acc[j]);
        bacc = fmaf(w, loadf(edge_b, k, f), bacc);
    }
#pragma unroll
    for (int j = 0; j < 6; ++j) Wfold[b * 768 + j * C + c] = acc[j];
    bfold[b * C + c] = bacc + loadf(bias, l * C + c, f);
}

// ---------- hcat = h @ Wcat_l.T  (M=N, K=128, Nout=512) ----------
__global__ __launch_bounds__(256) void gemm_hcat_kernel(
    const float* __restrict__ h, const float* __restrict__ Wcat,
    void* __restrict__ hcat, const int* __restrict__ flags, int allow32) {
    int bf16out = flags[0] || !allow32;
    __shared__ float As[64 * 68];    // padded rows (68 floats)
    __shared__ float Bs[64 * 64];    // xor-swizzled float4 columns
    int tid = threadIdx.x;
    int m0 = blockIdx.y * 64;
    int o0 = blockIdx.x * 64;
    int tr = tid >> 4, tc = tid & 15;
    float acc[4][4];
#pragma unroll
    for (int i = 0; i < 4; ++i)
#pragma unroll
        for (int j = 0; j < 4; ++j) acc[i][j] = 0.f;

    for (int kb = 0; kb < 2; ++kb) {
        if (kb) __syncthreads();
        for (int t = tid; t < 64 * 16; t += 256) {
            int r = t >> 4, cg = t & 15;
            int n = m0 + r;
            float4 v = make_float4(0.f, 0.f, 0.f, 0.f);
            if (n < N_NODES) v = ((const float4*)h)[(long long)n * 32 + kb * 16 + cg];
            *((float4*)&As[r * 68 + cg * 4]) = v;
        }
        for (int t = tid; t < 64 * 16; t += 256) {
            int r = t >> 4, cg = t & 15;
            float4 v = ((const float4*)Wcat)[(long long)(o0 + r) * 32 + kb * 16 + cg];
            int sw = cg ^ ((r >> 2) & 15);
            *((float4*)&Bs[r * 64 + sw * 4]) = v;
        }
        __syncthreads();
#pragma unroll
        for (int k4 = 0; k4 < 16; ++k4) {
            float4 a[4], b[4];
#pragma unroll
            for (int i = 0; i < 4; ++i)
                a[i] = *((const float4*)&As[(tr * 4 + i) * 68 + k4 * 4]);
#pragma unroll
            for (int j = 0; j < 4; ++j) {
                int r = tc * 4 + j;
                int sw = k4 ^ ((r >> 2) & 15);
                b[j] = *((const float4*)&Bs[r * 64 + sw * 4]);
            }
#pragma unroll
            for (int i = 0; i < 4; ++i)
#pragma unroll
                for (int j = 0; j < 4; ++j) {
                    acc[i][j] = fmaf(a[i].x, b[j].x, acc[i][j]);
                    acc[i][j] = fmaf(a[i].y, b[j].y, acc[i][j]);
                    acc[i][j] = fmaf(a[i].z, b[j].z, acc[i][j]);
                    acc[i][j] = fmaf(a[i].w, b[j].w, acc[i][j]);
                }
        }
    }
#pragma unroll
    for (int i = 0; i < 4; ++i) {
        int n = m0 + tr * 4 + i;
        if (n >= N_NODES) continue;
        if (bf16out) {
            ushort4 v;
            v.x = f2bf(acc[i][0]); v.y = f2bf(acc[i][1]);
            v.z = f2bf(acc[i][2]); v.w = f2bf(acc[i][3]);
            ((ushort4*)hcat)[(long long)n * 128 + (o0 >> 2) + tc] = v;
        } else {
            float4 v = make_float4(acc[i][0], acc[i][1], acc[i][2], acc[i][3]);
            ((float4*)hcat)[(long long)n * 128 + (o0 >> 2) + tc] = v;
        }
    }
}

// ---------- edge kernel: zf/zs -> sigmoid*softplus -> atomicMax agg ----------
__global__ __launch_bounds__(256) void edge_kernel(
    const void* __restrict__ edge_index,
    const void* __restrict__ edge_attr,
    const void* __restrict__ hcat,
    const float* __restrict__ Wfold, const float* __restrict__ bfold,
    unsigned int* __restrict__ agg, int layer,
    const int* __restrict__ flags, int allow32) {
    int f = flags[0];
    int i64 = flags[1];
    int hbf = f || !allow32;          // hcat stored as bf16?
    int tid = threadIdx.x;
    int q = tid & 31;
    int c0 = q * 4;
    const float* wf = Wfold + (long long)(2 * layer + 0) * 768;
    const float* ws = Wfold + (long long)(2 * layer + 1) * 768;
    float4 wfv[6], wsv[6];
#pragma unroll
    for (int j = 0; j < 6; ++j) {
        wfv[j] = *((const float4*)(wf + j * C + c0));
        wsv[j] = *((const float4*)(ws + j * C + c0));
    }
    float4 bfv = *((const float4*)(bfold + (long long)(2 * layer + 0) * C + c0));
    float4 bsv = *((const float4*)(bfold + (long long)(2 * layer + 1) * C + c0));

    int e = blockIdx.x * 8 + (tid >> 5);
    int estride = gridDim.x * 8;
    for (; e < N_EDGES; e += estride) {
        int src = loadi(edge_index, e, i64);
        int dst = loadi(edge_index, (long long)N_EDGES + e, i64);
        float hfi[4], hsi[4], hfj[4], hsj[4];
        if (hbf) {
            const ushort4* hb = (const ushort4*)hcat;   // row = 128 ushort4
            ushort4 a = hb[(long long)dst * 128 + q];
            ushort4 b = hb[(long long)dst * 128 + 32 + q];
            ushort4 c = hb[(long long)src * 128 + 64 + q];
            ushort4 d = hb[(long long)src * 128 + 96 + q];
            hfi[0]=bf2f(a.x); hfi[1]=bf2f(a.y); hfi[2]=bf2f(a.z); hfi[3]=bf2f(a.w);
            hsi[0]=bf2f(b.x); hsi[1]=bf2f(b.y); hsi[2]=bf2f(b.z); hsi[3]=bf2f(b.w);
            hfj[0]=bf2f(c.x); hfj[1]=bf2f(c.y); hfj[2]=bf2f(c.z); hfj[3]=bf2f(c.w);
            hsj[0]=bf2f(d.x); hsj[1]=bf2f(d.y); hsj[2]=bf2f(d.z); hsj[3]=bf2f(d.w);
        } else {
            const float4* hf = (const float4*)hcat;     // row = 128 float4
            float4 a = hf[(long long)dst * 128 + q];
            float4 b = hf[(long long)dst * 128 + 32 + q];
            float4 c = hf[(long long)src * 128 + 64 + q];
            float4 d = hf[(long long)src * 128 + 96 + q];
            hfi[0]=a.x; hfi[1]=a.y; hfi[2]=a.z; hfi[3]=a.w;
            hsi[0]=b.x; hsi[1]=b.y; hsi[2]=b.z; hsi[3]=b.w;
            hfj[0]=c.x; hfj[1]=c.y; hfj[2]=c.z; hfj[3]=c.w;
            hsj[0]=d.x; hsj[1]=d.y; hsj[2]=d.z; hsj[3]=d.w;
        }
        float ea[6];
#pragma unroll
        for (int j = 0; j < 6; ++j) ea[j] = loadf(edge_attr, (long long)e * 6 + j, f);
        const float* bfp = (const float*)&bfv;
        const float* bsp = (const float*)&bsv;
#pragma unroll
        for (int i = 0; i < 4; ++i) {
            float vf = hfi[i] + hfj[i] + bfp[i];
            float vs = hsi[i] + hsj[i] + bsp[i];
#pragma unroll
            for (int j = 0; j < 6; ++j) {
                vf = fmaf(ea[j], ((const float*)&wfv[j])[i], vf);
                vs = fmaf(ea[j], ((const float*)&wsv[j])[i], vs);
            }
            float sg = 1.f / (1.f + __expf(-vf));
            float sp = fmaxf(vs, 0.f) + __logf(1.f + __expf(-fabsf(vs)));
            float m = sg * sp;   // always >= 0, so uint-max == float-max
            atomicMax(agg + (long long)dst * C + c0 + i, __float_as_uint(m));
        }
    }
}

// ---------- h += BN(agg) ----------
__global__ __launch_bounds__(256) void bn_update_kernel(
    float* __restrict__ h, const float* __restrict__ agg,
    const void* __restrict__ bn_mean, const void* __restrict__ bn_var,
    const void* __restrict__ gamma, const void* __restrict__ beta, int layer,
    const int* __restrict__ flags) {
    int f = flags[0];
    int idx = blockIdx.x * blockDim.x + threadIdx.x;
    int n = idx >> 5;
    if (n >= N_NODES) return;
    int q = idx & 31, c0 = q * 4;
    float4 a = ((const float4*)agg)[(long long)n * 32 + q];
    float4 hv = ((float4*)h)[(long long)n * 32 + q];
    float* ap = (float*)&a;
    float* hp = (float*)&hv;
#pragma unroll
    for (int i = 0; i < 4; ++i) {
        long long o = (long long)layer * C + c0 + i;
        float mn = loadf(bn_mean, o, f);
        float vr = loadf(bn_var, o, f);
        float gm = loadf(gamma, o, f);
        float bt = loadf(beta, o, f);
        hp[i] += (ap[i] - mn) * rsqrtf(vr + BN_EPS) * gm + bt;
    }
    ((float4*)h)[(long long)n * 32 + q] = hv;
}

// ---------- out0 = h @ lin_W.T + lin_b ----------
__global__ __launch_bounds__(256) void final_kernel(
    const float* __restrict__ h, const void* __restrict__ lin_W,
    const void* __restrict__ lin_b, void* __restrict__ out,
    const int* __restrict__ flags) {
    int f = flags[0];
    int idx = blockIdx.x * blockDim.x + threadIdx.x;
    if (idx >= N_NODES * KOUT) return;
    int n = idx / KOUT, k = idx - n * KOUT;
    float acc = loadf(lin_b, k, f);
    const float* hr = h + (long long)n * C;
#pragma unroll 16
    for (int t = 0; t < C; ++t) acc = fmaf(hr[t], loadf(lin_W, (long long)k * C + t, f), acc);
    if (f) ((unsigned short*)out)[idx] = f2bf(acc);
    else   ((float*)out)[idx] = acc;
}

// ---------- out1 = h ----------
__global__ __launch_bounds__(256) void copy_h_kernel(
    const float* __restrict__ h, void* __restrict__ out,
    const int* __restrict__ flags) {
    int f = flags[0];
    long long i = (long long)blockIdx.x * blockDim.x + threadIdx.x;
    if (i >= (long long)N_NODES * C) return;
    long long o = (long long)N_NODES * KOUT + i;
    if (f) ((unsigned short*)out)[o] = f2bf(h[i]);
    else   ((float*)out)[o] = h[i];
}

extern "C" void kernel_launch(void* const* d_in, const int* in_sizes, int n_in,
                              void* d_out, int out_size, void* d_ws, size_t ws_size,
                              hipStream_t stream) {
    const void* x          = d_in[0];
    const void* edge_index = d_in[1];
    const void* edge_attr  = d_in[2];
    const void* node_W     = d_in[3];
    const void* node_b     = d_in[4];
    const void* edge_W     = d_in[5];
    const void* edge_b     = d_in[6];
    const void* Wf         = d_in[7];
    const void* bf         = d_in[8];
    const void* Ws         = d_in[9];
    const void* bs         = d_in[10];
    const void* gamma      = d_in[11];
    const void* beta       = d_in[12];
    const void* bn_mean    = d_in[13];
    const void* bn_var     = d_in[14];
    const void* lin_W      = d_in[15];
    const void* lin_b      = d_in[16];

    // workspace layout (static, deterministic)
    const size_t sz_h    = (size_t)N_NODES * C * 4;          // 25.6 MB
    const size_t sz_hc32 = (size_t)N_NODES * 512 * 4;        // 102.4 MB
    const size_t sz_hc16 = (size_t)N_NODES * 512 * 2;        // 51.2 MB
    const size_t sz_agg  = (size_t)N_NODES * C * 4;          // 25.6 MB
    const size_t sz_wcat = (size_t)NLAYERS * 512 * C * 4;
    const size_t sz_small = sz_wcat + 6 * 768 * 4 + 6 * C * 4 + 4096;
    const size_t need32 = sz_h + sz_hc32 + sz_agg + sz_small;
    int allow32 = (ws_size >= need32) ? 1 : 0;

    char* wsp = (char*)d_ws;
    size_t off = 0;
    auto alloc = [&](size_t bytes) -> void* {
        void* p = wsp + off; off += (bytes + 255) & ~(size_t)255; return p;
    };
    float* h     = (float*)alloc(sz_h);
    void*  hcat  = alloc(allow32 ? sz_hc32 : sz_hc16);
    float* agg   = (float*)alloc(sz_agg);
    float* Wcat  = (float*)alloc(sz_wcat);
    float* Wfold = (float*)alloc(6 * 768 * 4);
    float* bfold = (float*)alloc(6 * C * 4);
    int*   flags = (int*)alloc(256);

    detect_kernel<<<1, 64, 0, stream>>>((const unsigned int*)gamma,
                                        (const unsigned int*)edge_index, flags);
    node_embed_kernel<<<(N_NODES * 32 + 255) / 256, 256, 0, stream>>>(
        x, node_W, node_b, h, flags);
    pack_wcat_kernel<<<(NLAYERS * 512 * C + 255) / 256, 256, 0, stream>>>(
        Wf, Ws, Wcat, flags);
    fold_edge_kernel<<<2 * NLAYERS, C, 0, stream>>>(
        Wf, Ws, bf, bs, edge_W, edge_b, Wfold, bfold, flags);

    dim3 ggrid(512 / 64, (N_NODES + 63) / 64);
    for (int l = 0; l < NLAYERS; ++l) {
        gemm_hcat_kernel<<<ggrid, 256, 0, stream>>>(
            h, Wcat + (size_t)l * 512 * C, hcat, flags, allow32);
        hipMemsetAsync(agg, 0, sz_agg, stream);
        edge_kernel<<<8192, 256, 0, stream>>>(
            edge_index, edge_attr, hcat, Wfold, bfold,
            (unsigned int*)agg, l, flags, allow32);
        bn_update_kernel<<<(N_NODES * 32 + 255) / 256, 256, 0, stream>>>(
            h, agg, bn_mean, bn_var, gamma, beta, l, flags);
    }
    final_kernel<<<(N_NODES * KOUT + 255) / 256, 256, 0, stream>>>(
        h, lin_W, lin_b, d_out, flags);
    copy_h_kernel<<<(int)(((long long)N_NODES * C + 255) / 256), 256, 0, stream>>>(
        h, d_out, flags);
}

// Round 3
// 1513.616 us; speedup vs baseline: 2.6969x; 2.6969x over previous
//
#include <hip/hip_runtime.h>

#define N_NODES 50000
#define N_EDGES 800000
#define C 128
#define NLAYERS 3
#define KOUT 10
#define BN_EPS 1e-5f

// ---------- dtype helpers ----------
__device__ __forceinline__ float bf2f(unsigned short u) {
    return __uint_as_float(((unsigned int)u) << 16);
}
__device__ __forceinline__ unsigned short f2bf(float f) {
    unsigned int b = __float_as_uint(f);
    b += 0x7fff + ((b >> 16) & 1);   // round-to-nearest-even
    return (unsigned short)(b >> 16);
}
__device__ __forceinline__ float loadf(const void* p, long long i, int bf) {
    return bf ? bf2f(((const unsigned short*)p)[i]) : ((const float*)p)[i];
}
__device__ __forceinline__ int loadi(const void* p, long long i, int i64) {
    return i64 ? (int)((const long long*)p)[i] : ((const int*)p)[i];
}

// ---------- runtime dtype detection ----------
__global__ void detect_kernel(const unsigned int* __restrict__ gbits,
                              const unsigned int* __restrict__ ebits,
                              int* __restrict__ flags) {
    __shared__ int nz;
    if (threadIdx.x == 0) nz = 0;
    __syncthreads();
    if (threadIdx.x < 63 && ebits[threadIdx.x * 2 + 1] != 0u) atomicAdd(&nz, 1);
    __syncthreads();
    if (threadIdx.x == 0) {
        flags[0] = (gbits[0] == 0x3F803F80u) ? 1 : 0;  // float tensors are bf16
        flags[1] = (nz == 0) ? 1 : 0;                  // edge_index is int64
    }
}

// ---------- CSR build: degree histogram ----------
__global__ __launch_bounds__(256) void deg_kernel(
    const void* __restrict__ edge_index, int* __restrict__ deg,
    const int* __restrict__ flags) {
    int i64 = flags[1];
    int e = blockIdx.x * blockDim.x + threadIdx.x;
    if (e >= N_EDGES) return;
    int dst = loadi(edge_index, (long long)N_EDGES + e, i64);
    atomicAdd(&deg[dst], 1);
}

// ---------- CSR build: single-block scan over N+1 entries ----------
__global__ __launch_bounds__(1024) void scan_kernel(
    const int* __restrict__ deg, int* __restrict__ row, int* __restrict__ cursor) {
    __shared__ int ls[1024];
    const int ITEMS = 49;  // 1024*49 = 50176 >= N_NODES+1
    int t = threadIdx.x;
    int base = t * ITEMS;
    int s = 0;
    for (int i = 0; i < ITEMS; ++i) {
        int idx = base + i;
        if (idx < N_NODES) s += deg[idx];
    }
    ls[t] = s;
    __syncthreads();
    for (int off = 1; off < 1024; off <<= 1) {
        int v = (t >= off) ? ls[t - off] : 0;
        __syncthreads();
        ls[t] += v;
        __syncthreads();
    }
    int run = (t > 0) ? ls[t - 1] : 0;
    for (int i = 0; i < ITEMS; ++i) {
        int idx = base + i;
        if (idx <= N_NODES) {
            row[idx] = run;
            if (idx < N_NODES) {
                cursor[idx] = run;
                run += deg[idx];
            }
        }
    }
}

// ---------- CSR build: scatter src + fp32 edge_attr into sorted order ----------
__global__ __launch_bounds__(256) void scatter_kernel(
    const void* __restrict__ edge_index, const void* __restrict__ edge_attr,
    int* __restrict__ cursor, int* __restrict__ esrc, float* __restrict__ eatt,
    const int* __restrict__ flags) {
    int f = flags[0], i64 = flags[1];
    int e = blockIdx.x * blockDim.x + threadIdx.x;
    if (e >= N_EDGES) return;
    int src = loadi(edge_index, e, i64);
    int dst = loadi(edge_index, (long long)N_EDGES + e, i64);
    int pos = atomicAdd(&cursor[dst], 1);
    esrc[pos] = src;
#pragma unroll
    for (int j = 0; j < 6; ++j)
        eatt[(long long)pos * 6 + j] = loadf(edge_attr, (long long)e * 6 + j, f);
}

// ---------- h = x @ node_W.T + node_b ----------
__global__ __launch_bounds__(256) void node_embed_kernel(
    const void* __restrict__ x, const void* __restrict__ node_W,
    const void* __restrict__ node_b, float* __restrict__ h,
    const int* __restrict__ flags) {
    int f = flags[0];
    int gtid = blockIdx.x * blockDim.x + threadIdx.x;
    int n = gtid >> 5;
    if (n >= N_NODES) return;
    int c0 = (gtid & 31) * 4;
    float xv[7];
#pragma unroll
    for (int j = 0; j < 7; ++j) xv[j] = loadf(x, (long long)n * 7 + j, f);
    float4 acc;
    float* ap = (float*)&acc;
#pragma unroll
    for (int i = 0; i < 4; ++i) {
        int c = c0 + i;
        float a = loadf(node_b, c, f);
#pragma unroll
        for (int j = 0; j < 7; ++j) a = fmaf(xv[j], loadf(node_W, (long long)c * 7 + j, f), a);
        ap[i] = a;
    }
    ((float4*)h)[(long long)n * 32 + (gtid & 31)] = acc;
}

// ---------- pack Wcat[l][o][k]: rows [Wfi;Wsi;Wfj;Wsj] ----------
__global__ void pack_wcat_kernel(const void* __restrict__ Wf,
                                 const void* __restrict__ Ws,
                                 float* __restrict__ Wcat,
                                 const int* __restrict__ flags) {
    int f = flags[0];
    int idx = blockIdx.x * blockDim.x + threadIdx.x;
    if (idx >= NLAYERS * 512 * C) return;
    int k = idx & 127;
    int o = (idx >> 7) & 511;
    int l = idx >> 16;
    int c = o & 127;
    int g = o >> 7;
    long long base = (long long)l * C * 3 * C + (long long)c * 3 * C;
    float v;
    if (g == 0)      v = loadf(Wf, base + k, f);
    else if (g == 1) v = loadf(Ws, base + k, f);
    else if (g == 2) v = loadf(Wf, base + C + k, f);
    else             v = loadf(Ws, base + C + k, f);
    Wcat[idx] = v;
}

// ---------- fold edge path ----------
__global__ void fold_edge_kernel(const void* __restrict__ Wf,
                                 const void* __restrict__ Ws,
                                 const void* __restrict__ bf,
                                 const void* __restrict__ bs,
                                 const void* __restrict__ edge_W,
                                 const void* __restrict__ edge_b,
                                 float* __restrict__ Wfold,
                                 float* __restrict__ bfold,
                                 const int* __restrict__ flags) {
    int f = flags[0];
    int b = blockIdx.x;
    int l = b >> 1;
    int s = b & 1;
    int c = threadIdx.x;
    const void* W = s ? Ws : Wf;
    const void* bias = s ? bs : bf;
    long long wbase = (long long)l * C * 3 * C + (long long)c * 3 * C + 2 * C;
    float acc[6] = {0.f, 0.f, 0.f, 0.f, 0.f, 0.f};
    float bacc = 0.f;
    for (int k = 0; k < C; ++k) {
        float w = loadf(W, wbase + k, f);
#pragma unroll
        for (int j = 0; j < 6; ++j) acc[j] = fmaf(w, loadf(edge_W, k * 6 + j, f), acc[j]);
        bacc = fmaf(w, loadf(edge_b, k, f), bacc);
    }
#pragma unroll
    for (int j = 0; j < 6; ++j) Wfold[b * 768 + j * C + c] = acc[j];
    bfold[b * C + c] = bacc + loadf(bias, l * C + c, f);
}

// ---------- hcat = h @ Wcat_l.T  (M=N, K=128, Nout=512) ----------
__global__ __launch_bounds__(256) void gemm_hcat_kernel(
    const float* __restrict__ h, const float* __restrict__ Wcat,
    void* __restrict__ hcat, const int* __restrict__ flags, int allow32) {
    int bf16out = flags[0] || !allow32;
    __shared__ float As[64 * 68];
    __shared__ float Bs[64 * 64];
    int tid = threadIdx.x;
    int m0 = blockIdx.y * 64;
    int o0 = blockIdx.x * 64;
    int tr = tid >> 4, tc = tid & 15;
    float acc[4][4];
#pragma unroll
    for (int i = 0; i < 4; ++i)
#pragma unroll
        for (int j = 0; j < 4; ++j) acc[i][j] = 0.f;

    for (int kb = 0; kb < 2; ++kb) {
        if (kb) __syncthreads();
        for (int t = tid; t < 64 * 16; t += 256) {
            int r = t >> 4, cg = t & 15;
            int n = m0 + r;
            float4 v = make_float4(0.f, 0.f, 0.f, 0.f);
            if (n < N_NODES) v = ((const float4*)h)[(long long)n * 32 + kb * 16 + cg];
            *((float4*)&As[r * 68 + cg * 4]) = v;
        }
        for (int t = tid; t < 64 * 16; t += 256) {
            int r = t >> 4, cg = t & 15;
            float4 v = ((const float4*)Wcat)[(long long)(o0 + r) * 32 + kb * 16 + cg];
            int sw = cg ^ ((r >> 2) & 15);
            *((float4*)&Bs[r * 64 + sw * 4]) = v;
        }
        __syncthreads();
#pragma unroll
        for (int k4 = 0; k4 < 16; ++k4) {
            float4 a[4], b[4];
#pragma unroll
            for (int i = 0; i < 4; ++i)
                a[i] = *((const float4*)&As[(tr * 4 + i) * 68 + k4 * 4]);
#pragma unroll
            for (int j = 0; j < 4; ++j) {
                int r = tc * 4 + j;
                int sw = k4 ^ ((r >> 2) & 15);
                b[j] = *((const float4*)&Bs[r * 64 + sw * 4]);
            }
#pragma unroll
            for (int i = 0; i < 4; ++i)
#pragma unroll
                for (int j = 0; j < 4; ++j) {
                    acc[i][j] = fmaf(a[i].x, b[j].x, acc[i][j]);
                    acc[i][j] = fmaf(a[i].y, b[j].y, acc[i][j]);
                    acc[i][j] = fmaf(a[i].z, b[j].z, acc[i][j]);
                    acc[i][j] = fmaf(a[i].w, b[j].w, acc[i][j]);
                }
        }
    }
#pragma unroll
    for (int i = 0; i < 4; ++i) {
        int n = m0 + tr * 4 + i;
        if (n >= N_NODES) continue;
        if (bf16out) {
            ushort4 v;
            v.x = f2bf(acc[i][0]); v.y = f2bf(acc[i][1]);
            v.z = f2bf(acc[i][2]); v.w = f2bf(acc[i][3]);
            ((ushort4*)hcat)[(long long)n * 128 + (o0 >> 2) + tc] = v;
        } else {
            float4 v = make_float4(acc[i][0], acc[i][1], acc[i][2], acc[i][3]);
            ((float4*)hcat)[(long long)n * 128 + (o0 >> 2) + tc] = v;
        }
    }
}

// ---------- fused aggregation: CSR max + BN + residual, one wave per node ----------
__global__ __launch_bounds__(256) void agg_kernel(
    const int* __restrict__ esrc, const float* __restrict__ eatt,
    const int* __restrict__ row, const void* __restrict__ hcat,
    const float* __restrict__ Wfold, const float* __restrict__ bfold,
    float* __restrict__ h,
    const void* __restrict__ bn_mean, const void* __restrict__ bn_var,
    const void* __restrict__ gamma, const void* __restrict__ beta,
    int layer, const int* __restrict__ flags, int allow32) {
    int f = flags[0];
    int hbf = f || !allow32;
    int n = blockIdx.x * 4 + (threadIdx.x >> 6);   // wave id = node id
    if (n >= N_NODES) return;
    int lane = threadIdx.x & 63;
    int half = lane >> 5;
    int q = lane & 31;
    int c0 = q * 4;

    const float* wf = Wfold + (long long)(2 * layer + 0) * 768;
    const float* ws = Wfold + (long long)(2 * layer + 1) * 768;
    float4 wfv[6], wsv[6];
#pragma unroll
    for (int j = 0; j < 6; ++j) {
        wfv[j] = *((const float4*)(wf + j * C + c0));
        wsv[j] = *((const float4*)(ws + j * C + c0));
    }
    float4 bfv = *((const float4*)(bfold + (long long)(2 * layer + 0) * C + c0));
    float4 bsv = *((const float4*)(bfold + (long long)(2 * layer + 1) * C + c0));

    // i-part of dst node (read once), folded with bias
    float basef[4], bases[4];
    if (hbf) {
        const ushort4* hb = (const ushort4*)hcat;
        ushort4 a = hb[(long long)n * 128 + q];
        ushort4 b = hb[(long long)n * 128 + 32 + q];
        basef[0] = bf2f(a.x); basef[1] = bf2f(a.y); basef[2] = bf2f(a.z); basef[3] = bf2f(a.w);
        bases[0] = bf2f(b.x); bases[1] = bf2f(b.y); bases[2] = bf2f(b.z); bases[3] = bf2f(b.w);
    } else {
        const float4* hf = (const float4*)hcat;
        float4 a = hf[(long long)n * 128 + q];
        float4 b = hf[(long long)n * 128 + 32 + q];
        basef[0] = a.x; basef[1] = a.y; basef[2] = a.z; basef[3] = a.w;
        bases[0] = b.x; bases[1] = b.y; bases[2] = b.z; bases[3] = b.w;
    }
    const float* bfp = (const float*)&bfv;
    const float* bsp = (const float*)&bsv;
#pragma unroll
    for (int i = 0; i < 4; ++i) { basef[i] += bfp[i]; bases[i] += bsp[i]; }

    int r0 = row[n], r1 = row[n + 1];
    float mf[4] = {0.f, 0.f, 0.f, 0.f};   // msg > 0 always; empty segment -> 0

    for (int p = r0 + half; p < r1; p += 2) {
        int src = esrc[p];
        float hfj[4], hsj[4];
        if (hbf) {
            const ushort4* hb = (const ushort4*)hcat;
            ushort4 cjl = hb[(long long)src * 128 + 64 + q];
            ushort4 djl = hb[(long long)src * 128 + 96 + q];
            hfj[0] = bf2f(cjl.x); hfj[1] = bf2f(cjl.y); hfj[2] = bf2f(cjl.z); hfj[3] = bf2f(cjl.w);
            hsj[0] = bf2f(djl.x); hsj[1] = bf2f(djl.y); hsj[2] = bf2f(djl.z); hsj[3] = bf2f(djl.w);
        } else {
            const float4* hf4 = (const float4*)hcat;
            float4 cjl = hf4[(long long)src * 128 + 64 + q];
            float4 djl = hf4[(long long)src * 128 + 96 + q];
            hfj[0] = cjl.x; hfj[1] = cjl.y; hfj[2] = cjl.z; hfj[3] = cjl.w;
            hsj[0] = djl.x; hsj[1] = djl.y; hsj[2] = djl.z; hsj[3] = djl.w;
        }
        float ea[6];
#pragma unroll
        for (int j = 0; j < 6; ++j) ea[j] = eatt[(long long)p * 6 + j];
#pragma unroll
        for (int i = 0; i < 4; ++i) {
            float vf = basef[i] + hfj[i];
            float vs = bases[i] + hsj[i];
#pragma unroll
            for (int j = 0; j < 6; ++j) {
                vf = fmaf(ea[j], ((const float*)&wfv[j])[i], vf);
                vs = fmaf(ea[j], ((const float*)&wsv[j])[i], vs);
            }
            float sg = 1.f / (1.f + __expf(-vf));
            float sp = fmaxf(vs, 0.f) + __logf(1.f + __expf(-fabsf(vs)));
            mf[i] = fmaxf(mf[i], sg * sp);
        }
    }
    // combine the two halves of the wave
#pragma unroll
    for (int i = 0; i < 4; ++i) mf[i] = fmaxf(mf[i], __shfl_xor(mf[i], 32));

    if (half == 0) {
        float4 hv = ((float4*)h)[(long long)n * 32 + q];
        float* hp = (float*)&hv;
#pragma unroll
        for (int i = 0; i < 4; ++i) {
            long long o = (long long)layer * C + c0 + i;
            float mn = loadf(bn_mean, o, f);
            float vr = loadf(bn_var, o, f);
            float gm = loadf(gamma, o, f);
            float bt = loadf(beta, o, f);
            hp[i] += (mf[i] - mn) * rsqrtf(vr + BN_EPS) * gm + bt;
        }
        ((float4*)h)[(long long)n * 32 + q] = hv;
    }
}

// ---------- out0 = h @ lin_W.T + lin_b ----------
__global__ __launch_bounds__(256) void final_kernel(
    const float* __restrict__ h, const void* __restrict__ lin_W,
    const void* __restrict__ lin_b, void* __restrict__ out,
    const int* __restrict__ flags) {
    int f = flags[0];
    int idx = blockIdx.x * blockDim.x + threadIdx.x;
    if (idx >= N_NODES * KOUT) return;
    int n = idx / KOUT, k = idx - n * KOUT;
    float acc = loadf(lin_b, k, f);
    const float* hr = h + (long long)n * C;
#pragma unroll 16
    for (int t = 0; t < C; ++t) acc = fmaf(hr[t], loadf(lin_W, (long long)k * C + t, f), acc);
    if (f) ((unsigned short*)out)[idx] = f2bf(acc);
    else   ((float*)out)[idx] = acc;
}

// ---------- out1 = h ----------
__global__ __launch_bounds__(256) void copy_h_kernel(
    const float* __restrict__ h, void* __restrict__ out,
    const int* __restrict__ flags) {
    int f = flags[0];
    long long i = (long long)blockIdx.x * blockDim.x + threadIdx.x;
    if (i >= (long long)N_NODES * C) return;
    long long o = (long long)N_NODES * KOUT + i;
    if (f) ((unsigned short*)out)[o] = f2bf(h[i]);
    else   ((float*)out)[o] = h[i];
}

extern "C" void kernel_launch(void* const* d_in, const int* in_sizes, int n_in,
                              void* d_out, int out_size, void* d_ws, size_t ws_size,
                              hipStream_t stream) {
    const void* x          = d_in[0];
    const void* edge_index = d_in[1];
    const void* edge_attr  = d_in[2];
    const void* node_W     = d_in[3];
    const void* node_b     = d_in[4];
    const void* edge_W     = d_in[5];
    const void* edge_b     = d_in[6];
    const void* Wf         = d_in[7];
    const void* bf         = d_in[8];
    const void* Ws         = d_in[9];
    const void* bs         = d_in[10];
    const void* gamma      = d_in[11];
    const void* beta       = d_in[12];
    const void* bn_mean    = d_in[13];
    const void* bn_var     = d_in[14];
    const void* lin_W      = d_in[15];
    const void* lin_b      = d_in[16];

    const size_t sz_h    = (size_t)N_NODES * C * 4;
    const size_t sz_hc32 = (size_t)N_NODES * 512 * 4;
    const size_t sz_hc16 = (size_t)N_NODES * 512 * 2;
    const size_t sz_wcat = (size_t)NLAYERS * 512 * C * 4;
    const size_t sz_csr  = (size_t)(N_NODES + 1) * 4 * 3 + (size_t)N_EDGES * 4
                         + (size_t)N_EDGES * 6 * 4;
    const size_t sz_small = sz_wcat + 6 * 768 * 4 + 6 * C * 4 + 8192;
    const size_t need32 = sz_h + sz_hc32 + sz_csr + sz_small;
    int allow32 = (ws_size >= need32) ? 1 : 0;

    char* wsp = (char*)d_ws;
    size_t off = 0;
    auto alloc = [&](size_t bytes) -> void* {
        void* p = wsp + off; off += (bytes + 255) & ~(size_t)255; return p;
    };
    float* h      = (float*)alloc(sz_h);
    void*  hcat   = alloc(allow32 ? sz_hc32 : sz_hc16);
    int*   deg    = (int*)alloc((size_t)(N_NODES + 1) * 4);
    int*   rowp   = (int*)alloc((size_t)(N_NODES + 1) * 4);
    int*   cursor = (int*)alloc((size_t)(N_NODES + 1) * 4);
    int*   esrc   = (int*)alloc((size_t)N_EDGES * 4);
    float* eatt   = (float*)alloc((size_t)N_EDGES * 6 * 4);
    float* Wcat   = (float*)alloc(sz_wcat);
    float* Wfold  = (float*)alloc(6 * 768 * 4);
    float* bfold  = (float*)alloc(6 * C * 4);
    int*   flags  = (int*)alloc(256);

    detect_kernel<<<1, 64, 0, stream>>>((const unsigned int*)gamma,
                                        (const unsigned int*)edge_index, flags);
    // CSR build
    hipMemsetAsync(deg, 0, (size_t)(N_NODES + 1) * 4, stream);
    deg_kernel<<<(N_EDGES + 255) / 256, 256, 0, stream>>>(edge_index, deg, flags);
    scan_kernel<<<1, 1024, 0, stream>>>(deg, rowp, cursor);
    scatter_kernel<<<(N_EDGES + 255) / 256, 256, 0, stream>>>(
        edge_index, edge_attr, cursor, esrc, eatt, flags);

    node_embed_kernel<<<(N_NODES * 32 + 255) / 256, 256, 0, stream>>>(
        x, node_W, node_b, h, flags);
    pack_wcat_kernel<<<(NLAYERS * 512 * C + 255) / 256, 256, 0, stream>>>(
        Wf, Ws, Wcat, flags);
    fold_edge_kernel<<<2 * NLAYERS, C, 0, stream>>>(
        Wf, Ws, bf, bs, edge_W, edge_b, Wfold, bfold, flags);

    dim3 ggrid(512 / 64, (N_NODES + 63) / 64);
    for (int l = 0; l < NLAYERS; ++l) {
        gemm_hcat_kernel<<<ggrid, 256, 0, stream>>>(
            h, Wcat + (size_t)l * 512 * C, hcat, flags, allow32);
        agg_kernel<<<(N_NODES + 3) / 4, 256, 0, stream>>>(
            esrc, eatt, rowp, hcat, Wfold, bfold, h,
            bn_mean, bn_var, gamma, beta, l, flags, allow32);
    }
    final_kernel<<<(N_NODES * KOUT + 255) / 256, 256, 0, stream>>>(
        h, lin_W, lin_b, d_out, flags);
    copy_h_kernel<<<(int)(((long long)N_NODES * C + 255) / 256), 256, 0, stream>>>(
        h, d_out, flags);
}

// Round 4
// 1292.975 us; speedup vs baseline: 3.1571x; 1.1706x over previous
//
#include <hip/hip_runtime.h>

#define N_NODES 50000
#define N_EDGES 800000
#define C 128
#define NLAYERS 3
#define KOUT 10
#define BN_EPS 1e-5f

typedef float v2f __attribute__((ext_vector_type(2)));
typedef __attribute__((ext_vector_type(4))) float f32x4;
typedef __attribute__((ext_vector_type(8))) short s16x8;

// ---------- dtype helpers ----------
__device__ __forceinline__ float bf2f(unsigned short u) {
    return __uint_as_float(((unsigned int)u) << 16);
}
__device__ __forceinline__ unsigned short f2bf(float f) {
    unsigned int b = __float_as_uint(f);
    b += 0x7fff + ((b >> 16) & 1);   // round-to-nearest-even
    return (unsigned short)(b >> 16);
}
__device__ __forceinline__ float blo(unsigned int u) { return __uint_as_float(u << 16); }
__device__ __forceinline__ float bhi(unsigned int u) { return __uint_as_float(u & 0xffff0000u); }
__device__ __forceinline__ float loadf(const void* p, long long i, int bf) {
    return bf ? bf2f(((const unsigned short*)p)[i]) : ((const float*)p)[i];
}
__device__ __forceinline__ int loadi(const void* p, long long i, int i64) {
    return i64 ? (int)((const long long*)p)[i] : ((const int*)p)[i];
}

// ---------- runtime dtype detection ----------
__global__ void detect_kernel(const unsigned int* __restrict__ gbits,
                              const unsigned int* __restrict__ ebits,
                              int* __restrict__ flags) {
    __shared__ int nz;
    if (threadIdx.x == 0) nz = 0;
    __syncthreads();
    if (threadIdx.x < 63 && ebits[threadIdx.x * 2 + 1] != 0u) atomicAdd(&nz, 1);
    __syncthreads();
    if (threadIdx.x == 0) {
        flags[0] = (gbits[0] == 0x3F803F80u) ? 1 : 0;  // float tensors are bf16
        flags[1] = (nz == 0) ? 1 : 0;                  // edge_index is int64
    }
}

// ---------- CSR build ----------
__global__ __launch_bounds__(256) void deg_kernel(
    const void* __restrict__ edge_index, int* __restrict__ deg,
    const int* __restrict__ flags) {
    int i64 = flags[1];
    int e = blockIdx.x * blockDim.x + threadIdx.x;
    if (e >= N_EDGES) return;
    int dst = loadi(edge_index, (long long)N_EDGES + e, i64);
    atomicAdd(&deg[dst], 1);
}

__global__ __launch_bounds__(1024) void scan_kernel(
    const int* __restrict__ deg, int* __restrict__ row, int* __restrict__ cursor) {
    __shared__ int ls[1024];
    const int ITEMS = 49;  // 1024*49 = 50176 >= N_NODES+1
    int t = threadIdx.x;
    int base = t * ITEMS;
    int s = 0;
    for (int i = 0; i < ITEMS; ++i) {
        int idx = base + i;
        if (idx < N_NODES) s += deg[idx];
    }
    ls[t] = s;
    __syncthreads();
    for (int off = 1; off < 1024; off <<= 1) {
        int v = (t >= off) ? ls[t - off] : 0;
        __syncthreads();
        ls[t] += v;
        __syncthreads();
    }
    int run = (t > 0) ? ls[t - 1] : 0;
    for (int i = 0; i < ITEMS; ++i) {
        int idx = base + i;
        if (idx <= N_NODES) {
            row[idx] = run;
            if (idx < N_NODES) {
                cursor[idx] = run;
                run += deg[idx];
            }
        }
    }
}

// scatter src + fp32 edge_attr (stride 8, float4-aligned) into dst-sorted order
__global__ __launch_bounds__(256) void scatter_kernel(
    const void* __restrict__ edge_index, const void* __restrict__ edge_attr,
    int* __restrict__ cursor, int* __restrict__ esrc, float* __restrict__ eatt,
    const int* __restrict__ flags) {
    int f = flags[0], i64 = flags[1];
    int e = blockIdx.x * blockDim.x + threadIdx.x;
    if (e >= N_EDGES) return;
    int src = loadi(edge_index, e, i64);
    int dst = loadi(edge_index, (long long)N_EDGES + e, i64);
    int pos = atomicAdd(&cursor[dst], 1);
    esrc[pos] = src;
    float a0 = loadf(edge_attr, (long long)e * 6 + 0, f);
    float a1 = loadf(edge_attr, (long long)e * 6 + 1, f);
    float a2 = loadf(edge_attr, (long long)e * 6 + 2, f);
    float a3 = loadf(edge_attr, (long long)e * 6 + 3, f);
    float a4 = loadf(edge_attr, (long long)e * 6 + 4, f);
    float a5 = loadf(edge_attr, (long long)e * 6 + 5, f);
    ((float4*)eatt)[(long long)pos * 2 + 0] = make_float4(a0, a1, a2, a3);
    ((float4*)eatt)[(long long)pos * 2 + 1] = make_float4(a4, a5, 0.f, 0.f);
}

// ---------- h = x @ node_W.T + node_b (fp32 h + bf16 shadow) ----------
__global__ __launch_bounds__(256) void node_embed_kernel(
    const void* __restrict__ x, const void* __restrict__ node_W,
    const void* __restrict__ node_b, float* __restrict__ h,
    unsigned short* __restrict__ h16, const int* __restrict__ flags) {
    int f = flags[0];
    int gtid = blockIdx.x * blockDim.x + threadIdx.x;
    int n = gtid >> 5;
    if (n >= N_NODES) return;
    int c0 = (gtid & 31) * 4;
    float xv[7];
#pragma unroll
    for (int j = 0; j < 7; ++j) xv[j] = loadf(x, (long long)n * 7 + j, f);
    float4 acc;
    float* ap = (float*)&acc;
#pragma unroll
    for (int i = 0; i < 4; ++i) {
        int c = c0 + i;
        float a = loadf(node_b, c, f);
#pragma unroll
        for (int j = 0; j < 7; ++j) a = fmaf(xv[j], loadf(node_W, (long long)c * 7 + j, f), a);
        ap[i] = a;
    }
    ((float4*)h)[(long long)n * 32 + (gtid & 31)] = acc;
    ushort4 s;
    s.x = f2bf(ap[0]); s.y = f2bf(ap[1]); s.z = f2bf(ap[2]); s.w = f2bf(ap[3]);
    ((ushort4*)h16)[(long long)n * 32 + (gtid & 31)] = s;
}

// ---------- pack Wcat (fp32 + bf16): rows [Wfi;Wsi;Wfj;Wsj] ----------
__global__ void pack_wcat_kernel(const void* __restrict__ Wf,
                                 const void* __restrict__ Ws,
                                 float* __restrict__ Wcat,
                                 unsigned short* __restrict__ Wcat16,
                                 const int* __restrict__ flags) {
    int f = flags[0];
    int idx = blockIdx.x * blockDim.x + threadIdx.x;
    if (idx >= NLAYERS * 512 * C) return;
    int k = idx & 127;
    int o = (idx >> 7) & 511;
    int l = idx >> 16;
    int c = o & 127;
    int g = o >> 7;
    long long base = (long long)l * C * 3 * C + (long long)c * 3 * C;
    float v;
    if (g == 0)      v = loadf(Wf, base + k, f);
    else if (g == 1) v = loadf(Ws, base + k, f);
    else if (g == 2) v = loadf(Wf, base + C + k, f);
    else             v = loadf(Ws, base + C + k, f);
    Wcat[idx] = v;
    Wcat16[idx] = f2bf(v);
}

// ---------- fold edge path ----------
__global__ void fold_edge_kernel(const void* __restrict__ Wf,
                                 const void* __restrict__ Ws,
                                 const void* __restrict__ bf,
                                 const void* __restrict__ bs,
                                 const void* __restrict__ edge_W,
                                 const void* __restrict__ edge_b,
                                 float* __restrict__ Wfold,
                                 float* __restrict__ bfold,
                                 const int* __restrict__ flags) {
    int f = flags[0];
    int b = blockIdx.x;
    int l = b >> 1;
    int s = b & 1;
    int c = threadIdx.x;
    const void* W = s ? Ws : Wf;
    const void* bias = s ? bs : bf;
    long long wbase = (long long)l * C * 3 * C + (long long)c * 3 * C + 2 * C;
    float acc[6] = {0.f, 0.f, 0.f, 0.f, 0.f, 0.f};
    float bacc = 0.f;
    for (int k = 0; k < C; ++k) {
        float w = loadf(W, wbase + k, f);
#pragma unroll
        for (int j = 0; j < 6; ++j) acc[j] = fmaf(w, loadf(edge_W, k * 6 + j, f), acc[j]);
        bacc = fmaf(w, loadf(edge_b, k, f), bacc);
    }
#pragma unroll
    for (int j = 0; j < 6; ++j) Wfold[b * 768 + j * C + c] = acc[j];
    bfold[b * C + c] = bacc + loadf(bias, l * C + c, f);
}

// ---------- pack lin_W/lin_b to fp32 ----------
__global__ void pack_lin_kernel(const void* __restrict__ lin_W,
                                const void* __restrict__ lin_b,
                                float* __restrict__ linWf, float* __restrict__ linbf,
                                const int* __restrict__ flags) {
    int f = flags[0];
    int idx = blockIdx.x * blockDim.x + threadIdx.x;
    if (idx < KOUT * C) linWf[idx] = loadf(lin_W, idx, f);
    if (idx < KOUT) linbf[idx] = loadf(lin_b, idx, f);
}

// ---------- MFMA GEMM (bf16 mode): hcat = h16 @ Wcat16_l.T, bf16 out ----------
// 128x128 block tile, K=128 in one LDS stage, XOR-swizzled 16B chunks.
__global__ __launch_bounds__(256) void gemm_hcat_mfma(
    const unsigned short* __restrict__ h16,
    const unsigned short* __restrict__ Wcat16,
    unsigned short* __restrict__ hcat, const int* __restrict__ flags) {
    if (flags[0] == 0) return;   // fp32 mode handled by vector kernel
    __shared__ unsigned short As[128 * 128];
    __shared__ unsigned short Bs[128 * 128];
    int tid = threadIdx.x;
    int m0 = blockIdx.y * 128, o0 = blockIdx.x * 128;
    // stage A and B: 128 rows x 16 chunks of 8 bf16 (16B), chunk c stored at c^(r&7)
    for (int t = tid; t < 128 * 16; t += 256) {
        int r = t >> 4, c = t & 15;
        int sw = (c ^ (r & 7)) << 3;
        int gm = m0 + r;
        uint4 va = make_uint4(0u, 0u, 0u, 0u);
        if (gm < N_NODES) va = ((const uint4*)(h16 + (size_t)gm * 128))[c];
        *((uint4*)&As[r * 128 + sw]) = va;
        uint4 vb = ((const uint4*)(Wcat16 + (size_t)(o0 + r) * 128))[c];
        *((uint4*)&Bs[r * 128 + sw]) = vb;
    }
    __syncthreads();
    int wid = tid >> 6, lane = tid & 63;
    int m0w = (wid >> 1) * 64, n0w = (wid & 1) * 64;
    int rr = lane & 15;
    int kq = lane >> 4;          // k-quad
    f32x4 acc[4][4];
#pragma unroll
    for (int i = 0; i < 4; ++i)
#pragma unroll
        for (int j = 0; j < 4; ++j) acc[i][j] = (f32x4){0.f, 0.f, 0.f, 0.f};

#pragma unroll
    for (int ks = 0; ks < 4; ++ks) {
        int chunk = ks * 4 + kq;
        s16x8 a[4], b[4];
#pragma unroll
        for (int mt = 0; mt < 4; ++mt) {
            int R = m0w + mt * 16 + rr;
            a[mt] = *((const s16x8*)&As[R * 128 + ((chunk ^ (R & 7)) << 3)]);
        }
#pragma unroll
        for (int nt = 0; nt < 4; ++nt) {
            int R = n0w + nt * 16 + rr;
            b[nt] = *((const s16x8*)&Bs[R * 128 + ((chunk ^ (R & 7)) << 3)]);
        }
#pragma unroll
        for (int mt = 0; mt < 4; ++mt)
#pragma unroll
            for (int nt = 0; nt < 4; ++nt)
                acc[mt][nt] = __builtin_amdgcn_mfma_f32_16x16x32_bf16(
                    a[mt], b[nt], acc[mt][nt], 0, 0, 0);
    }
    // C/D layout: col = lane&15, row = (lane>>4)*4 + reg  [m89-verified]
    int cw = lane & 15, rw = kq * 4;
#pragma unroll
    for (int mt = 0; mt < 4; ++mt) {
#pragma unroll
        for (int reg = 0; reg < 4; ++reg) {
            int m = m0 + m0w + mt * 16 + rw + reg;
            if (m >= N_NODES) continue;
            unsigned short* dst = hcat + (size_t)m * 512 + o0 + n0w + cw;
#pragma unroll
            for (int nt = 0; nt < 4; ++nt)
                dst[nt * 16] = f2bf(acc[mt][nt][reg]);
        }
    }
}

// ---------- fp32-mode fallback GEMM (vector FMA) ----------
__global__ __launch_bounds__(256) void gemm_hcat_fp32(
    const float* __restrict__ h, const float* __restrict__ Wcat,
    void* __restrict__ hcat, const int* __restrict__ flags, int allow32) {
    if (flags[0] == 1) return;   // bf16 mode handled by MFMA kernel
    int bf16out = !allow32;
    __shared__ float Asm[64 * 68];
    __shared__ float Bsm[64 * 64];
    int tid = threadIdx.x;
    int m0 = blockIdx.y * 64;
    int o0 = blockIdx.x * 64;
    int tr = tid >> 4, tc = tid & 15;
    float acc[4][4];
#pragma unroll
    for (int i = 0; i < 4; ++i)
#pragma unroll
        for (int j = 0; j < 4; ++j) acc[i][j] = 0.f;

    for (int kb = 0; kb < 2; ++kb) {
        if (kb) __syncthreads();
        for (int t = tid; t < 64 * 16; t += 256) {
            int r = t >> 4, cg = t & 15;
            int n = m0 + r;
            float4 v = make_float4(0.f, 0.f, 0.f, 0.f);
            if (n < N_NODES) v = ((const float4*)h)[(long long)n * 32 + kb * 16 + cg];
            *((float4*)&Asm[r * 68 + cg * 4]) = v;
        }
        for (int t = tid; t < 64 * 16; t += 256) {
            int r = t >> 4, cg = t & 15;
            float4 v = ((const float4*)Wcat)[(long long)(o0 + r) * 32 + kb * 16 + cg];
            int sw = cg ^ ((r >> 2) & 15);
            *((float4*)&Bsm[r * 64 + sw * 4]) = v;
        }
        __syncthreads();
#pragma unroll
        for (int k4 = 0; k4 < 16; ++k4) {
            float4 a[4], b[4];
#pragma unroll
            for (int i = 0; i < 4; ++i)
                a[i] = *((const float4*)&Asm[(tr * 4 + i) * 68 + k4 * 4]);
#pragma unroll
            for (int j = 0; j < 4; ++j) {
                int r = tc * 4 + j;
                int sw = k4 ^ ((r >> 2) & 15);
                b[j] = *((const float4*)&Bsm[r * 64 + sw * 4]);
            }
#pragma unroll
            for (int i = 0; i < 4; ++i)
#pragma unroll
                for (int j = 0; j < 4; ++j) {
                    acc[i][j] = fmaf(a[i].x, b[j].x, acc[i][j]);
                    acc[i][j] = fmaf(a[i].y, b[j].y, acc[i][j]);
                    acc[i][j] = fmaf(a[i].z, b[j].z, acc[i][j]);
                    acc[i][j] = fmaf(a[i].w, b[j].w, acc[i][j]);
                }
        }
    }
#pragma unroll
    for (int i = 0; i < 4; ++i) {
        int n = m0 + tr * 4 + i;
        if (n >= N_NODES) continue;
        if (bf16out) {
            ushort4 v;
            v.x = f2bf(acc[i][0]); v.y = f2bf(acc[i][1]);
            v.z = f2bf(acc[i][2]); v.w = f2bf(acc[i][3]);
            ((ushort4*)hcat)[(long long)n * 128 + (o0 >> 2) + tc] = v;
        } else {
            float4 v = make_float4(acc[i][0], acc[i][1], acc[i][2], acc[i][3]);
            ((float4*)hcat)[(long long)n * 128 + (o0 >> 2) + tc] = v;
        }
    }
}

// ---------- fused aggregation: CSR max + BN + residual + h16 update ----------
__global__ __launch_bounds__(256) void agg_kernel(
    const int* __restrict__ esrc, const float* __restrict__ eatt,
    const int* __restrict__ row, const void* __restrict__ hcat,
    const float* __restrict__ Wfold, const float* __restrict__ bfold,
    float* __restrict__ h, unsigned short* __restrict__ h16,
    const void* __restrict__ bn_mean, const void* __restrict__ bn_var,
    const void* __restrict__ gamma, const void* __restrict__ beta,
    int layer, const int* __restrict__ flags, int allow32) {
    int f = flags[0];
    int hbf = f || !allow32;
    int n = blockIdx.x * 4 + (threadIdx.x >> 6);
    if (n >= N_NODES) return;
    int lane = threadIdx.x & 63;
    int half = lane >> 5;
    int q = lane & 31;
    int c0 = q * 4;

    const float* wf = Wfold + (long long)(2 * layer + 0) * 768;
    const float* ws = Wfold + (long long)(2 * layer + 1) * 768;
    v2f wf2[6][2], ws2[6][2];
#pragma unroll
    for (int j = 0; j < 6; ++j) {
        float4 a = *((const float4*)(wf + j * C + c0));
        float4 b = *((const float4*)(ws + j * C + c0));
        wf2[j][0] = (v2f){a.x, a.y}; wf2[j][1] = (v2f){a.z, a.w};
        ws2[j][0] = (v2f){b.x, b.y}; ws2[j][1] = (v2f){b.z, b.w};
    }
    float4 bfv = *((const float4*)(bfold + (long long)(2 * layer + 0) * C + c0));
    float4 bsv = *((const float4*)(bfold + (long long)(2 * layer + 1) * C + c0));

    // dst i-part (read once), folded with bias
    v2f bf0, bf1, bs0, bs1;
    if (hbf) {
        const uint2* hb = (const uint2*)hcat;
        uint2 a = hb[(long long)n * 128 + q];
        uint2 b = hb[(long long)n * 128 + 32 + q];
        bf0 = (v2f){blo(a.x) + bfv.x, bhi(a.x) + bfv.y};
        bf1 = (v2f){blo(a.y) + bfv.z, bhi(a.y) + bfv.w};
        bs0 = (v2f){blo(b.x) + bsv.x, bhi(b.x) + bsv.y};
        bs1 = (v2f){blo(b.y) + bsv.z, bhi(b.y) + bsv.w};
    } else {
        const float4* hf = (const float4*)hcat;
        float4 a = hf[(long long)n * 128 + q];
        float4 b = hf[(long long)n * 128 + 32 + q];
        bf0 = (v2f){a.x + bfv.x, a.y + bfv.y};
        bf1 = (v2f){a.z + bfv.z, a.w + bfv.w};
        bs0 = (v2f){b.x + bsv.x, b.y + bsv.y};
        bs1 = (v2f){b.z + bsv.z, b.w + bsv.w};
    }

    int r0 = row[n], r1 = row[n + 1];
    float mf[4] = {0.f, 0.f, 0.f, 0.f};

    for (int p = r0 + half; p < r1; p += 2) {
        int src = esrc[p];
        v2f vf0, vf1, vs0, vs1;
        if (hbf) {
            const uint2* hb = (const uint2*)hcat;
            uint2 cj = hb[(long long)src * 128 + 64 + q];
            uint2 dj = hb[(long long)src * 128 + 96 + q];
            vf0 = bf0 + (v2f){blo(cj.x), bhi(cj.x)};
            vf1 = bf1 + (v2f){blo(cj.y), bhi(cj.y)};
            vs0 = bs0 + (v2f){blo(dj.x), bhi(dj.x)};
            vs1 = bs1 + (v2f){blo(dj.y), bhi(dj.y)};
        } else {
            const float4* hf4 = (const float4*)hcat;
            float4 cj = hf4[(long long)src * 128 + 64 + q];
            float4 dj = hf4[(long long)src * 128 + 96 + q];
            vf0 = bf0 + (v2f){cj.x, cj.y};
            vf1 = bf1 + (v2f){cj.z, cj.w};
            vs0 = bs0 + (v2f){dj.x, dj.y};
            vs1 = bs1 + (v2f){dj.z, dj.w};
        }
        float4 e0 = ((const float4*)eatt)[(long long)p * 2 + 0];
        float4 e1 = ((const float4*)eatt)[(long long)p * 2 + 1];
        float eaj[6] = {e0.x, e0.y, e0.z, e0.w, e1.x, e1.y};
#pragma unroll
        for (int j = 0; j < 6; ++j) {
            v2f ej = (v2f){eaj[j], eaj[j]};
            vf0 = __builtin_elementwise_fma(ej, wf2[j][0], vf0);
            vf1 = __builtin_elementwise_fma(ej, wf2[j][1], vf1);
            vs0 = __builtin_elementwise_fma(ej, ws2[j][0], vs0);
            vs1 = __builtin_elementwise_fma(ej, ws2[j][1], vs1);
        }
        float zf[4] = {vf0.x, vf0.y, vf1.x, vf1.y};
        float zs[4] = {vs0.x, vs0.y, vs1.x, vs1.y};
#pragma unroll
        for (int i = 0; i < 4; ++i) {
            float sg = 1.f / (1.f + __expf(-zf[i]));
            float sp = fmaxf(zs[i], 0.f) + __logf(1.f + __expf(-fabsf(zs[i])));
            mf[i] = fmaxf(mf[i], sg * sp);
        }
    }
#pragma unroll
    for (int i = 0; i < 4; ++i) mf[i] = fmaxf(mf[i], __shfl_xor(mf[i], 32));

    if (half == 0) {
        float4 hv = ((float4*)h)[(long long)n * 32 + q];
        float* hp = (float*)&hv;
#pragma unroll
        for (int i = 0; i < 4; ++i) {
            long long o = (long long)layer * C + c0 + i;
            float mn = loadf(bn_mean, o, f);
            float vr = loadf(bn_var, o, f);
            float gm = loadf(gamma, o, f);
            float bt = loadf(beta, o, f);
            hp[i] += (mf[i] - mn) * rsqrtf(vr + BN_EPS) * gm + bt;
        }
        ((float4*)h)[(long long)n * 32 + q] = hv;
        ushort4 s;
        s.x = f2bf(hp[0]); s.y = f2bf(hp[1]); s.z = f2bf(hp[2]); s.w = f2bf(hp[3]);
        ((ushort4*)h16)[(long long)n * 32 + q] = s;
    }
}

// ---------- out0 = h @ lin_W.T + lin_b ----------
__global__ __launch_bounds__(256) void final_kernel(
    const float* __restrict__ h, const float* __restrict__ linWf,
    const float* __restrict__ linbf, void* __restrict__ out,
    const int* __restrict__ flags) {
    int f = flags[0];
    int idx = blockIdx.x * blockDim.x + threadIdx.x;
    if (idx >= N_NODES * KOUT) return;
    int n = idx / KOUT, k = idx - n * KOUT;
    const float4* hr = (const float4*)(h + (long long)n * C);
    const float4* wr = (const float4*)(linWf + (long long)k * C);
    float acc = linbf[k];
#pragma unroll 8
    for (int t = 0; t < 32; ++t) {
        float4 a = hr[t], b = wr[t];
        acc = fmaf(a.x, b.x, acc); acc = fmaf(a.y, b.y, acc);
        acc = fmaf(a.z, b.z, acc); acc = fmaf(a.w, b.w, acc);
    }
    if (f) ((unsigned short*)out)[idx] = f2bf(acc);
    else   ((float*)out)[idx] = acc;
}

// ---------- out1 = h ----------
__global__ __launch_bounds__(256) void copy_h_kernel(
    const float* __restrict__ h, void* __restrict__ out,
    const int* __restrict__ flags) {
    int f = flags[0];
    long long i = (long long)blockIdx.x * blockDim.x + threadIdx.x;
    if (i >= (long long)N_NODES * C) return;
    long long o = (long long)N_NODES * KOUT + i;
    if (f) ((unsigned short*)out)[o] = f2bf(h[i]);
    else   ((float*)out)[o] = h[i];
}

extern "C" void kernel_launch(void* const* d_in, const int* in_sizes, int n_in,
                              void* d_out, int out_size, void* d_ws, size_t ws_size,
                              hipStream_t stream) {
    const void* x          = d_in[0];
    const void* edge_index = d_in[1];
    const void* edge_attr  = d_in[2];
    const void* node_W     = d_in[3];
    const void* node_b     = d_in[4];
    const void* edge_W     = d_in[5];
    const void* edge_b     = d_in[6];
    const void* Wf         = d_in[7];
    const void* bf         = d_in[8];
    const void* Ws         = d_in[9];
    const void* bs         = d_in[10];
    const void* gamma      = d_in[11];
    const void* beta       = d_in[12];
    const void* bn_mean    = d_in[13];
    const void* bn_var     = d_in[14];
    const void* lin_W      = d_in[15];
    const void* lin_b      = d_in[16];

    const size_t sz_h    = (size_t)N_NODES * C * 4;
    const size_t sz_h16  = (size_t)N_NODES * C * 2;
    const size_t sz_hc32 = (size_t)N_NODES * 512 * 4;
    const size_t sz_hc16 = (size_t)N_NODES * 512 * 2;
    const size_t sz_wcat = (size_t)NLAYERS * 512 * C * 4;
    const size_t sz_csr  = (size_t)(N_NODES + 1) * 4 * 3 + (size_t)N_EDGES * 4
                         + (size_t)N_EDGES * 8 * 4;
    const size_t sz_small = sz_wcat + sz_wcat / 2 + 6 * 768 * 4 + 6 * C * 4
                          + KOUT * C * 4 + 4096 + 8192;
    const size_t need_full = sz_h + sz_h16 + sz_hc32 + sz_csr + sz_small;
    int allow32 = (ws_size >= need_full) ? 1 : 0;

    char* wsp = (char*)d_ws;
    size_t off = 0;
    auto alloc = [&](size_t bytes) -> void* {
        void* p = wsp + off; off += (bytes + 255) & ~(size_t)255; return p;
    };
    float*          h      = (float*)alloc(sz_h);
    unsigned short* h16    = (unsigned short*)alloc(sz_h16);
    void*           hcat   = alloc(allow32 ? sz_hc32 : sz_hc16);
    int*            deg    = (int*)alloc((size_t)(N_NODES + 1) * 4);
    int*            rowp   = (int*)alloc((size_t)(N_NODES + 1) * 4);
    int*            cursor = (int*)alloc((size_t)(N_NODES + 1) * 4);
    int*            esrc   = (int*)alloc((size_t)N_EDGES * 4);
    float*          eatt   = (float*)alloc((size_t)N_EDGES * 8 * 4);
    float*          Wcat   = (float*)alloc(sz_wcat);
    unsigned short* Wcat16 = (unsigned short*)alloc(sz_wcat / 2);
    float*          Wfold  = (float*)alloc(6 * 768 * 4);
    float*          bfold  = (float*)alloc(6 * C * 4);
    float*          linWf  = (float*)alloc(KOUT * C * 4);
    float*          linbf  = (float*)alloc(KOUT * 4);
    int*            flags  = (int*)alloc(256);

    detect_kernel<<<1, 64, 0, stream>>>((const unsigned int*)gamma,
                                        (const unsigned int*)edge_index, flags);
    hipMemsetAsync(deg, 0, (size_t)(N_NODES + 1) * 4, stream);
    deg_kernel<<<(N_EDGES + 255) / 256, 256, 0, stream>>>(edge_index, deg, flags);
    scan_kernel<<<1, 1024, 0, stream>>>(deg, rowp, cursor);
    scatter_kernel<<<(N_EDGES + 255) / 256, 256, 0, stream>>>(
        edge_index, edge_attr, cursor, esrc, eatt, flags);

    node_embed_kernel<<<(N_NODES * 32 + 255) / 256, 256, 0, stream>>>(
        x, node_W, node_b, h, h16, flags);
    pack_wcat_kernel<<<(NLAYERS * 512 * C + 255) / 256, 256, 0, stream>>>(
        Wf, Ws, Wcat, Wcat16, flags);
    fold_edge_kernel<<<2 * NLAYERS, C, 0, stream>>>(
        Wf, Ws, bf, bs, edge_W, edge_b, Wfold, bfold, flags);
    pack_lin_kernel<<<(KOUT * C + 255) / 256, 256, 0, stream>>>(
        lin_W, lin_b, linWf, linbf, flags);

    dim3 gmfma(512 / 128, (N_NODES + 127) / 128);
    dim3 gfp32(512 / 64, (N_NODES + 63) / 64);
    for (int l = 0; l < NLAYERS; ++l) {
        gemm_hcat_mfma<<<gmfma, 256, 0, stream>>>(
            h16, Wcat16 + (size_t)l * 512 * C, (unsigned short*)hcat, flags);
        gemm_hcat_fp32<<<gfp32, 256, 0, stream>>>(
            h, Wcat + (size_t)l * 512 * C, hcat, flags, allow32);
        agg_kernel<<<(N_NODES + 3) / 4, 256, 0, stream>>>(
            esrc, eatt, rowp, hcat, Wfold, bfold, h, h16,
            bn_mean, bn_var, gamma, beta, l, flags, allow32);
    }
    final_kernel<<<(N_NODES * KOUT + 255) / 256, 256, 0, stream>>>(
        h, linWf, linbf, d_out, flags);
    copy_h_kernel<<<(int)(((long long)N_NODES * C + 255) / 256), 256, 0, stream>>>(
        h, d_out, flags);
}